// Round 21
// baseline (8711.265 us; speedup 1.0000x reference)
//
#include <hip/hip_runtime.h>
#include <hip/hip_bf16.h>
#include <math.h>

// ---------------------------------------------------------------------------
// ROUND 21 — speed: OCPT=8 f64 trunk convs (2x ILP), f32 noise branch + l
// path, barrier-free wave-level harmonic kernel, z-batched phase kernels.
// Phase-critical numerics (f64 trunk -> f -> f64 cumsum) bit-identical to
// the round-20 pass (absmax 0.0390625).
// ---------------------------------------------------------------------------

#define DEVFN __device__ __forceinline__

__global__ __launch_bounds__(256) void pickx(
    const float* __restrict__ A, int* __restrict__ flag) {
  __shared__ float red[256];
  float m = 0.f;
  for (int i = threadIdx.x; i < 524288; i += 256) m = fmaxf(m, fabsf(A[i]));
  red[threadIdx.x] = m; __syncthreads();
  for (int o = 128; o > 0; o >>= 1) {
    if (threadIdx.x < o) red[threadIdx.x] = fmaxf(red[threadIdx.x], red[threadIdx.x + o]);
    __syncthreads();
  }
  if (threadIdx.x == 0) *flag = (red[0] > 1.0001f) ? 0 : 1;  // 0 -> A is x
}

__global__ __launch_bounds__(256) void selcopy(
    const float* __restrict__ A, const float* __restrict__ B,
    const int* __restrict__ flag, float* __restrict__ X, float* __restrict__ NZ) {
  int i = blockIdx.x * 256 + threadIdx.x;
  const float* xs = (*flag == 0) ? A : B;
  const float* ns = (*flag == 0) ? B : A;
  X[i] = xs[i]; NZ[i] = ns[i];
}

// ---------------- f64 register-tiled direct conv (trunk) ------------------
template<typename TIN,int IC,int OC,int KH,int KW,int SH,int PH_,int PW,
         int OCPT,int OWPT,int EPI>
__global__ __launch_bounds__(128) void convkd(
    const TIN* __restrict__ in, const float* __restrict__ wg,
    double* __restrict__ out, int IH, int IW, int OH, int OW) {
  const int tid = threadIdx.x;
  const int WT  = OW >> 9;                 // OW/(128*OWPT), OWPT=4
  const int wt  = blockIdx.x % WT;
  const int ocg = blockIdx.x / WT;
  const int oh  = blockIdx.y;
  const int oc0 = ocg * OCPT;
  const int ow0 = (wt * 128 + tid) * OWPT;

  double acc[OCPT][OWPT];
#pragma unroll
  for (int j = 0; j < OCPT; ++j)
#pragma unroll
    for (int i = 0; i < OWPT; ++i) acc[j][i] = 0.0;

  for (int ic = 0; ic < IC; ++ic) {
    const TIN* inp = in + (size_t)ic * IH * IW;
#pragma unroll
    for (int kh = 0; kh < KH; ++kh) {
      int ih = oh * SH + kh - PH_;
      if (ih < 0 || ih >= IH) continue;
      const TIN* row = inp + (size_t)ih * IW;
      double xin[OWPT + KW - 1];
#pragma unroll
      for (int i = 0; i < OWPT + KW - 1; ++i) {
        int iw = ow0 - PW + i;
        xin[i] = (iw >= 0 && iw < IW) ? (double)row[iw] : 0.0;
      }
      const float* wbase = wg + ((size_t)ic * KH + kh) * KW;
#pragma unroll
      for (int kw = 0; kw < KW; ++kw) {
#pragma unroll
        for (int j = 0; j < OCPT; ++j) {
          double wv = (double)wbase[(size_t)(oc0 + j) * IC * KH * KW + kw];
#pragma unroll
          for (int i = 0; i < OWPT; ++i)
            acc[j][i] = fma(xin[i + kw], wv, acc[j][i]);
        }
      }
    }
  }
#pragma unroll
  for (int j = 0; j < OCPT; ++j) {
    double* op = out + ((size_t)(oc0 + j) * OH + oh) * OW + ow0;
#pragma unroll
    for (int i = 0; i < OWPT; ++i) {
      double v = acc[j][i];
      if (EPI == 1) v = v > 0.0 ? v : 0.2 * v;
      if (EPI == 2) v = v * v;
      op[i] = v;
    }
  }
}

// ---------------- f32 conv (noise branch; TIN may be f64 PRE) -------------
template<typename TIN,int IC,int OC,int KH,int KW,int SH,int PH_,int PW,
         int OCPT,int OWPT,int EPI>
__global__ __launch_bounds__(128) void convf(
    const TIN* __restrict__ in, const float* __restrict__ wg,
    float* __restrict__ out, int IH, int IW, int OH, int OW) {
  const int tid = threadIdx.x;
  const int WT  = OW / (128 * OWPT);
  const int wt  = blockIdx.x % WT;
  const int ocg = blockIdx.x / WT;
  const int oh  = blockIdx.y;
  const int oc0 = ocg * OCPT;
  const int ow0 = (wt * 128 + tid) * OWPT;

  float acc[OCPT][OWPT];
#pragma unroll
  for (int j = 0; j < OCPT; ++j)
#pragma unroll
    for (int i = 0; i < OWPT; ++i) acc[j][i] = 0.f;

  for (int ic = 0; ic < IC; ++ic) {
    const TIN* inp = in + (size_t)ic * IH * IW;
#pragma unroll
    for (int kh = 0; kh < KH; ++kh) {
      int ih = oh * SH + kh - PH_;
      if (ih < 0 || ih >= IH) continue;
      const TIN* row = inp + (size_t)ih * IW;
      float xin[OWPT + KW - 1];
#pragma unroll
      for (int i = 0; i < OWPT + KW - 1; ++i) {
        int iw = ow0 - PW + i;
        xin[i] = (iw >= 0 && iw < IW) ? (float)row[iw] : 0.f;
      }
      const float* wbase = wg + ((size_t)ic * KH + kh) * KW;
#pragma unroll
      for (int kw = 0; kw < KW; ++kw) {
#pragma unroll
        for (int j = 0; j < OCPT; ++j) {
          float wv = wbase[(size_t)(oc0 + j) * IC * KH * KW + kw];
#pragma unroll
          for (int i = 0; i < OWPT; ++i)
            acc[j][i] = fmaf(xin[i + kw], wv, acc[j][i]);
        }
      }
    }
  }
#pragma unroll
  for (int j = 0; j < OCPT; ++j) {
    float* op = out + ((size_t)(oc0 + j) * OH + oh) * OW + ow0;
#pragma unroll
    for (int i = 0; i < OWPT; ++i) {
      float v = acc[j][i];
      if (EPI == 1) v = v > 0.f ? v : 0.2f * v;
      if (EPI == 2) v = v * v;
      op[i] = v;
    }
  }
}

// ---------------- tp post: l (f32) + f (f64) ------------------------------
__global__ __launch_bounds__(256) void tpostd(
    const double* __restrict__ p, const float* __restrict__ centers,
    const float* __restrict__ erbs, float* __restrict__ lfr, double* __restrict__ ffr) {
  int idx = blockIdx.x * 256 + threadIdx.x;      // 128*512
  int fr = idx & 511;
  int o  = idx >> 9;
  double p0 = p[(size_t)o * 512 + fr];
  double p1 = p[(size_t)(128 + o) * 512 + fr];
  lfr[idx] = (float)(p0 * p0);
  ffr[idx] = (double)centers[o] + tanh(p1) * 0.5 * (double)erbs[o];
}

// ---------------- f32 half-pixel resize 512 -> 8192 -----------------------
__global__ __launch_bounds__(256) void resizef(
    const float* __restrict__ in, float* __restrict__ out) {
  int idx = blockIdx.x * 256 + threadIdx.x;      // 256 rows * 8192
  int t = idx & 8191;
  int r = idx >> 13;
  float c = ((float)t + 0.5f) * (1.0f / 16.0f) - 0.5f;
  int i0 = (int)floorf(c);
  float w = c - (float)i0;
  int ia = i0 < 0 ? 0 : i0;
  int ib = (i0 + 1 > 511) ? 511 : i0 + 1;
  const float* rp = in + (size_t)r * 512;
  out[idx] = rp[ia] * (1.f - w) + rp[ib] * w;
}

// ---------------- noise bank f32 ------------------------------------------
__global__ __launch_bounds__(256) void noisebankf(
    const float* __restrict__ nz, const float* __restrict__ mags,
    float* __restrict__ filt) {
  __shared__ float ct[17][32], st[17][32];
  for (int i = threadIdx.x; i < 17 * 32; i += 256) {
    int k = i >> 5, t = i & 31;
    double ang = (M_PI / 16.0) * (double)(k * t);
    ct[k][t] = (float)cos(ang);
    st[k][t] = (float)sin(ang);
  }
  __syncthreads();
  int frm = blockIdx.x * 256 + threadIdx.x;   // 0..8191
  int base = frm * 16;
  float x[32];
#pragma unroll
  for (int t = 0; t < 32; ++t) {
    int idx = base + t;
    x[t] = (idx < 131072) ? nz[idx] : 0.f;
  }
  float a[17], bb[17];
#pragma unroll
  for (int k = 0; k < 17; ++k) {
    float ra = 0.f, rb = 0.f;
#pragma unroll
    for (int t = 0; t < 32; ++t) {
      ra = fmaf(x[t], ct[k][t], ra);
      rb = fmaf(x[t], st[k][t], rb);
    }
    float m  = mags[(size_t)k * 8192 + frm];
    float wk = (k == 0 || k == 16) ? 1.0f : 2.0f;
    float cf = wk * m * (1.0f / 32.0f);
    a[k] = cf * ra; bb[k] = cf * rb;
  }
  float* fo = filt + (size_t)frm * 32;
#pragma unroll
  for (int t = 0; t < 32; ++t) {
    float s = 0.f;
#pragma unroll
    for (int k = 0; k < 17; ++k)
      s = fmaf(a[k], ct[k][t], fmaf(bb[k], st[k][t], s));
    fo[t] = s;
  }
}

// ---------------- phase increment (f64, identical to round 20) ------------
DEVFN double phase_inc_d(const double* __restrict__ fr_row, int t) {
  double c = ((double)t + 0.5) * (1.0 / 256.0) - 0.5;
  double fl = floor(c);
  int i0 = (int)fl;
  double w = c - fl;
  int ia = i0 < 0 ? 0 : i0;
  int ib = (i0 + 1 > 511) ? 511 : i0 + 1;
  double f = (1.0 - w) * fr_row[ia] + w * fr_row[ib];
  f = f < 20.0 ? 20.0 : (f > 5512.5 ? 5512.5 : f);
  return f * (2.0 * M_PI / 11025.0);
}

// ---------------- per-256-chunk totals, z-batched -------------------------
__global__ __launch_bounds__(256) void phaseA256(
    const double* __restrict__ FFR, double* __restrict__ CTOT) {
  int lane = threadIdx.x & 63, wid = threadIdx.x >> 6;
  int o = blockIdx.y, b = blockIdx.z;
  int ch = blockIdx.x * 4 + wid;            // 0..511
  const double* fr = FFR + (size_t)b * 65536 + (size_t)o * 512;
  int t0 = ch * 256 + lane * 4;
  double s = phase_inc_d(fr, t0) + phase_inc_d(fr, t0 + 1)
           + phase_inc_d(fr, t0 + 2) + phase_inc_d(fr, t0 + 3);
#pragma unroll
  for (int off = 32; off > 0; off >>= 1) s += __shfl_xor(s, off);
  if (lane == 0) CTOT[((size_t)b * 128 + o) * 512 + ch] = s;
}

__global__ __launch_bounds__(128) void phaseB4(
    const double* __restrict__ CTOT, double* __restrict__ CBAS) {
  int o = threadIdx.x;                 // 0..127
  int b = blockIdx.x;
  const double* ct = CTOT + ((size_t)b * 128 + o) * 512;
  double* cb = CBAS + ((size_t)b * 128 + o) * 512;
  double base = 0.0;
  for (int c = 0; c < 512; ++c) { cb[c] = base; base += ct[c]; }
}

// ---------------- sin: f64 range reduce + f32 sin -------------------------
DEVFN float sinx(double ph) {
  double k = rint(ph * 0.15915494309189535);
  float r = (float)__builtin_fma(-k, 6.283185307179586, ph);
  return sinf(r);
}

// ---------------- harm: barrier-free, one wave per 256-sample chunk -------
__global__ __launch_bounds__(256) void harm2(
    const double* __restrict__ FFR, const float* __restrict__ LFR32,
    const double* __restrict__ CBAS, const float* __restrict__ FILT,
    float* __restrict__ out) {
  int tid = threadIdx.x, lane = tid & 63, wid = tid >> 6;
  int b = blockIdx.y;
  int ch = 16 + blockIdx.x * 4 + wid;        // chunks 16..495
  int t0 = ch * 256 + lane * 4;
  const double* ffr  = FFR  + (size_t)b * 65536;
  const float*  lfr  = LFR32 + (size_t)b * 65536;
  const double* cbas = CBAS + (size_t)b * 65536;
  const float*  filt = FILT + (size_t)b * 262144;
  float* ob = out + (size_t)b * 122880;

  int fis[4]; float wls[4];
#pragma unroll
  for (int k = 0; k < 4; ++k) {
    double c = ((double)(t0 + k) + 0.5) * (1.0 / 256.0) - 0.5;
    double fl = floor(c);
    fis[k] = (int)fl;                        // t>=4096 -> [15,495]
    wls[k] = (float)(c - fl);
  }
  float acc0 = 0.f, acc1 = 0.f, acc2 = 0.f, acc3 = 0.f;

  for (int o = 0; o < 128; ++o) {
    const double* fr = ffr + (size_t)o * 512;
    double a0 = phase_inc_d(fr, t0 + 0);
    double a1 = phase_inc_d(fr, t0 + 1);
    double a2 = phase_inc_d(fr, t0 + 2);
    double a3 = phase_inc_d(fr, t0 + 3);
    double l0 = a0, l1 = l0 + a1, l2 = l1 + a2, l3 = l2 + a3;
    double v = l3;                            // wave-inclusive scan
#pragma unroll
    for (int off = 1; off < 64; off <<= 1) {
      double n = __shfl_up(v, off);
      if (lane >= off) v += n;
    }
    double excl = cbas[(size_t)o * 512 + ch] + (v - l3);

    const float* lr = lfr + (size_t)o * 512;
    float lv0 = lr[fis[0]] * (1.f - wls[0]) + lr[fis[0] + 1] * wls[0];
    float lv1 = lr[fis[1]] * (1.f - wls[1]) + lr[fis[1] + 1] * wls[1];
    float lv2 = lr[fis[2]] * (1.f - wls[2]) + lr[fis[2] + 1] * wls[2];
    float lv3 = lr[fis[3]] * (1.f - wls[3]) + lr[fis[3] + 1] * wls[3];

    acc0 = fmaf(sinx(excl + l0), lv0, acc0);
    acc1 = fmaf(sinx(excl + l1), lv1, acc1);
    acc2 = fmaf(sinx(excl + l2), lv2, acc2);
    acc3 = fmaf(sinx(excl + l3), lv3, acc3);
  }
#pragma unroll
  for (int k = 0; k < 4; ++k) {
    int t = t0 + k;
    int r = t >> 4, j = t & 15;
    float nz = filt[r * 32 + j] + filt[(r - 1) * 32 + 16 + j];
    float h = (k == 0) ? acc0 : (k == 1) ? acc1 : (k == 2) ? acc2 : acc3;
    ob[t - 4096] = h + nz;
  }
}

// ---------------------------------------------------------------------------
extern "C" void kernel_launch(void* const* d_in, const int* in_sizes, int n_in,
                              void* d_out, int out_size, void* d_ws, size_t ws_size,
                              hipStream_t stream) {
  (void)out_size; (void)ws_size;
  const float *big0 = nullptr, *big1 = nullptr;
  const float *m1w=nullptr,*m2w=nullptr,*m3w=nullptr,*m4w=nullptr,*m5w=nullptr;
  const float *tpw=nullptr,*n1w=nullptr,*n2w=nullptr,*n3w=nullptr,*n4w=nullptr;
  const float *centers=nullptr,*erbs=nullptr;
  int n55296 = 0, n128 = 0, nbig = 0;
  for (int i = 0; i < n_in; ++i) {
    const float* p = (const float*)d_in[i];
    switch (in_sizes[i]) {
      case 524288: if (nbig++ == 0) big0 = p; else big1 = p; break;
      case 864:    m1w = p; break;
      case 27648:  m2w = p; break;
      case 55296:  if (n55296++ == 0) m3w = p; else m5w = p; break;
      case 110592: m4w = p; break;
      case 576:    tpw = p; break;
      case 26112:  n1w = p; break;
      case 13056:  n2w = p; break;
      case 1536:   n3w = p; break;
      case 2448:   n4w = p; break;
      case 128:    if (n128++ == 0) centers = p; else erbs = p; break;
      default: break;
    }
  }

  char* ws = (char*)d_ws;
  double* R1    = (double*)(ws + 0);           // 67.1MB
  double* R2    = (double*)(ws + 67108864);    // 33.5MB
  double* PRE   = (double*)(ws + 100663296);   // 16.8MB
  double* P     = (double*)(ws + 117440512);   // 1MB
  float*  NB1   = (float*) (ws + 118489088);   // 0.5MB
  float*  NB1R  = (float*) (ws + 119013376);   // 8.4MB
  float*  NB2   = (float*) (ws + 127401984);   // 1MB
  float*  NB3   = (float*) (ws + 128450560);   // 0.5MB
  float*  MAGS  = (float*) (ws + 128974848);   // 0.56MB
  double* FFR   = (double*)(ws + 129531904);   // 2MB   (x4 batches)
  float*  LFR32 = (float*) (ws + 131629056);   // 1MB   (x4)
  double* CTOT  = (double*)(ws + 132677632);   // 2MB   (x4)
  double* CBAS  = (double*)(ws + 134774784);   // 2MB   (x4)
  float*  FILT  = (float*) (ws + 136871936);   // 4MB   (x4)
  float*  XBUF  = (float*) (ws + 141066240);   // 2MB
  float*  NZBUF = (float*) (ws + 143163392);   // 2MB
  int*    FLAG  = (int*)   (ws + 145260544);

  pickx<<<dim3(1),256,0,stream>>>(big0, FLAG);
  selcopy<<<dim3(2048),256,0,stream>>>(big0, big1, FLAG, XBUF, NZBUF);

  for (int b = 0; b < 4; ++b) {
    const float* xb  = XBUF  + (size_t)b * 131072;
    const float* nzb = NZBUF + (size_t)b * 131072;
    double* FFRb  = FFR   + (size_t)b * 65536;
    float*  LFRb  = LFR32 + (size_t)b * 65536;
    float*  FILTb = FILT  + (size_t)b * 262144;

    // trunk (f64, OCPT=8)
    convkd<float, 1,32,3,9,1,1,4, 8,4,1><<<dim3(4,256,1),128,0,stream>>>(xb, m1w, R1, 256,512,256,512);
    convkd<double,32,32,9,3,1,4,1, 8,4,1><<<dim3(4,256,1),128,0,stream>>>(R1, m2w, R2, 256,512,256,512);
    convkd<double,32,64,3,9,1,1,4, 8,4,1><<<dim3(8,256,1),128,0,stream>>>(R2, m3w, R1, 256,512,256,512);
    convkd<double,64,64,3,9,2,1,4, 8,4,1><<<dim3(8,128,1),128,0,stream>>>(R1, m4w, R2, 256,512,128,512);
    convkd<double,64,32,3,9,1,1,4, 8,4,1><<<dim3(4,128,1),128,0,stream>>>(R2, m5w, PRE, 128,512,128,512);
    convkd<double,32,2,3,3,1,1,1, 2,4,0><<<dim3(1,128,1),128,0,stream>>>(PRE, tpw, P, 128,512,128,512);
    tpostd<<<dim3(256),256,0,stream>>>(P, centers, erbs, LFRb, FFRb);
    // noise branch (f32)
    convf<double,32,16,17,3,8,8,1, 4,1,1><<<dim3(16,16,1),128,0,stream>>>(PRE, n1w, NB1, 128,512,16,512);
    resizef<<<dim3(8192),256,0,stream>>>(NB1, NB1R);
    convf<float,16,16,17,3,8,8,1, 4,4,1><<<dim3(64,2,1),128,0,stream>>>(NB1R, n2w, NB2, 16,8192,2,8192);
    convf<float,16,16,2,3,1,0,1, 4,4,1><<<dim3(64,1,1),128,0,stream>>>(NB2, n3w, NB3, 2,8192,1,8192);
    convf<float,16,17,3,3,1,1,1, 1,4,2><<<dim3(272,1,1),128,0,stream>>>(NB3, n4w, MAGS, 1,8192,1,8192);
    noisebankf<<<dim3(32),256,0,stream>>>(nzb, MAGS, FILTb);
  }

  // phase + harmonic, z-batched
  phaseA256<<<dim3(128,128,4),256,0,stream>>>(FFR, CTOT);
  phaseB4<<<dim3(4),128,0,stream>>>(CTOT, CBAS);
  harm2<<<dim3(120,4),256,0,stream>>>(FFR, LFR32, CBAS, FILT, (float*)d_out);
}

// Round 23
// 8249.294 us; speedup vs baseline: 1.0560x; 1.0560x over previous
//
#include <hip/hip_runtime.h>
#include <hip/hip_bf16.h>
#include <math.h>

// ---------------------------------------------------------------------------
// ROUND 23 — round 22 with corrected noise-branch geometry:
//   NB1  per batch = 16x16x512  = 131072 els (stride fixed, was 8192)
//   NB1R per batch = 16x16x8192 = 2097152 els, aliased onto R1f (dead there)
//   resize grid covers 256 rows/batch (was 16)
// Everything else identical to round 22 (z-batched f64-accum convs, harm
// split over 4 osc-groups, parallel pickmax).
// ---------------------------------------------------------------------------

#define DEVFN __device__ __forceinline__

__global__ void zeroi(int* __restrict__ f) { if (threadIdx.x == 0) f[0] = 0; }

__global__ __launch_bounds__(256) void pickmax(
    const float* __restrict__ A, int* __restrict__ m) {
  __shared__ float s[256];
  int base = blockIdx.x * 2048 + threadIdx.x;
  float mx = 0.f;
#pragma unroll
  for (int k = 0; k < 8; ++k) mx = fmaxf(mx, fabsf(A[base + k * 256]));
  s[threadIdx.x] = mx; __syncthreads();
  for (int o = 128; o > 0; o >>= 1) {
    if (threadIdx.x < o) s[threadIdx.x] = fmaxf(s[threadIdx.x], s[threadIdx.x + o]);
    __syncthreads();
  }
  if (threadIdx.x == 0) atomicMax(m, __float_as_int(s[0]));  // s[0] >= 0
}

__global__ __launch_bounds__(256) void selcopy(
    const float* __restrict__ A, const float* __restrict__ B,
    const int* __restrict__ m, float* __restrict__ X, float* __restrict__ NZ) {
  int i = blockIdx.x * 256 + threadIdx.x;
  bool aIsX = __int_as_float(m[0]) > 1.0001f;   // x ~ N(0,1): max ~4.7 > 1
  const float* xs = aIsX ? A : B;
  const float* ns = aIsX ? B : A;
  X[i] = xs[i]; NZ[i] = ns[i];
}

// ---------------- z-batched conv: f32 in/out, f64 accumulate ---------------
template<int IC,int OC,int KH,int KW,int SH,int PH_,int PW,int OCPT,int OWPT,int EPI>
__global__ __launch_bounds__(128) void convz(
    const float* __restrict__ in, const float* __restrict__ wg,
    float* __restrict__ out, int IH, int IW, int OH, int OW,
    size_t inStride, size_t outStride) {
  const int tid = threadIdx.x;
  const int WT  = OW / (128 * OWPT);
  const int wt  = blockIdx.x % WT;
  const int ocg = blockIdx.x / WT;
  const int oh  = blockIdx.y;
  const int oc0 = ocg * OCPT;
  const int ow0 = (wt * 128 + tid) * OWPT;
  const float* inb  = in  + (size_t)blockIdx.z * inStride;
  float*       outb = out + (size_t)blockIdx.z * outStride;

  double acc[OCPT][OWPT];
#pragma unroll
  for (int j = 0; j < OCPT; ++j)
#pragma unroll
    for (int i = 0; i < OWPT; ++i) acc[j][i] = 0.0;

  for (int ic = 0; ic < IC; ++ic) {
    const float* inp = inb + (size_t)ic * IH * IW;
#pragma unroll
    for (int kh = 0; kh < KH; ++kh) {
      int ih = oh * SH + kh - PH_;
      if (ih < 0 || ih >= IH) continue;
      const float* row = inp + (size_t)ih * IW;
      double xin[OWPT + KW - 1];
#pragma unroll
      for (int i = 0; i < OWPT + KW - 1; ++i) {
        int iw = ow0 - PW + i;
        xin[i] = (iw >= 0 && iw < IW) ? (double)row[iw] : 0.0;
      }
      const float* wbase = wg + ((size_t)ic * KH + kh) * KW;
#pragma unroll
      for (int kw = 0; kw < KW; ++kw) {
#pragma unroll
        for (int j = 0; j < OCPT; ++j) {
          double wv = (double)wbase[(size_t)(oc0 + j) * IC * KH * KW + kw];
#pragma unroll
          for (int i = 0; i < OWPT; ++i)
            acc[j][i] = fma(xin[i + kw], wv, acc[j][i]);
        }
      }
    }
  }
#pragma unroll
  for (int j = 0; j < OCPT; ++j) {
    float* op = outb + ((size_t)(oc0 + j) * OH + oh) * OW + ow0;
#pragma unroll
    for (int i = 0; i < OWPT; ++i) {
      double v = acc[j][i];
      if (EPI == 1) v = v > 0.0 ? v : 0.2 * v;
      if (EPI == 2) v = v * v;
      op[i] = (float)v;
    }
  }
}

// ---------------- tp post: l (f32) + f (f64), z-batched --------------------
__global__ __launch_bounds__(256) void tpostz(
    const float* __restrict__ Pf, const float* __restrict__ centers,
    const float* __restrict__ erbs, float* __restrict__ lfr,
    double* __restrict__ ffr, int g) {
  int idx = blockIdx.x * 256 + threadIdx.x;      // 128*512
  int z = blockIdx.y;
  int b = g * 2 + z;
  int fr = idx & 511;
  int o  = idx >> 9;
  const float* p = Pf + (size_t)z * 131072;
  double p0 = (double)p[o * 512 + fr];
  double p1 = (double)p[65536 + o * 512 + fr];
  lfr[(size_t)b * 65536 + idx] = (float)(p0 * p0);
  ffr[(size_t)b * 65536 + idx] = (double)centers[o] + tanh(p1) * 0.5 * (double)erbs[o];
}

// ---------------- f32 half-pixel resize 512 -> 8192, 256 rows, z-batched ---
__global__ __launch_bounds__(256) void resizefz(
    const float* __restrict__ in, float* __restrict__ out) {
  int idx = blockIdx.x * 256 + threadIdx.x;      // 0..2097151 (256 rows)
  int t = idx & 8191;
  int r = idx >> 13;                             // 0..255
  const float* rp = in + (size_t)blockIdx.y * 131072 + (size_t)r * 512;
  float c = ((float)t + 0.5f) * (1.0f / 16.0f) - 0.5f;
  int i0 = (int)floorf(c);
  float w = c - (float)i0;
  int ia = i0 < 0 ? 0 : i0;
  int ib = (i0 + 1 > 511) ? 511 : i0 + 1;
  out[(size_t)blockIdx.y * 2097152 + idx] = rp[ia] * (1.f - w) + rp[ib] * w;
}

// ---------------- noise bank f32, z-batched --------------------------------
__global__ __launch_bounds__(256) void noisebankz(
    const float* __restrict__ NZBUF, const float* __restrict__ MAGS,
    float* __restrict__ FILT, int g) {
  __shared__ float ct[17][32], st[17][32];
  for (int i = threadIdx.x; i < 17 * 32; i += 256) {
    int k = i >> 5, t = i & 31;
    double ang = (M_PI / 16.0) * (double)(k * t);
    ct[k][t] = (float)cos(ang);
    st[k][t] = (float)sin(ang);
  }
  __syncthreads();
  int z = blockIdx.y;
  int b = g * 2 + z;
  const float* nz   = NZBUF + (size_t)b * 131072;
  const float* mags = MAGS + (size_t)z * 139264;
  float* filt = FILT + (size_t)b * 262144;
  int frm = blockIdx.x * 256 + threadIdx.x;   // 0..8191
  int base = frm * 16;
  float x[32];
#pragma unroll
  for (int t = 0; t < 32; ++t) {
    int idx = base + t;
    x[t] = (idx < 131072) ? nz[idx] : 0.f;
  }
  float a[17], bb[17];
#pragma unroll
  for (int k = 0; k < 17; ++k) {
    float ra = 0.f, rb = 0.f;
#pragma unroll
    for (int t = 0; t < 32; ++t) {
      ra = fmaf(x[t], ct[k][t], ra);
      rb = fmaf(x[t], st[k][t], rb);
    }
    float m  = mags[(size_t)k * 8192 + frm];
    float wk = (k == 0 || k == 16) ? 1.0f : 2.0f;
    float cf = wk * m * (1.0f / 32.0f);
    a[k] = cf * ra; bb[k] = cf * rb;
  }
  float* fo = filt + (size_t)frm * 32;
#pragma unroll
  for (int t = 0; t < 32; ++t) {
    float s = 0.f;
#pragma unroll
    for (int k = 0; k < 17; ++k)
      s = fmaf(a[k], ct[k][t], fmaf(bb[k], st[k][t], s));
    fo[t] = s;
  }
}

// ---------------- phase increment (f64, identical to the pass) -------------
DEVFN double phase_inc_d(const double* __restrict__ fr_row, int t) {
  double c = ((double)t + 0.5) * (1.0 / 256.0) - 0.5;
  double fl = floor(c);
  int i0 = (int)fl;
  double w = c - fl;
  int ia = i0 < 0 ? 0 : i0;
  int ib = (i0 + 1 > 511) ? 511 : i0 + 1;
  double f = (1.0 - w) * fr_row[ia] + w * fr_row[ib];
  f = f < 20.0 ? 20.0 : (f > 5512.5 ? 5512.5 : f);
  return f * (2.0 * M_PI / 11025.0);
}

__global__ __launch_bounds__(256) void phaseA256(
    const double* __restrict__ FFR, double* __restrict__ CTOT) {
  int lane = threadIdx.x & 63, wid = threadIdx.x >> 6;
  int o = blockIdx.y, b = blockIdx.z;
  int ch = blockIdx.x * 4 + wid;            // 0..511
  const double* fr = FFR + (size_t)b * 65536 + (size_t)o * 512;
  int t0 = ch * 256 + lane * 4;
  double s = phase_inc_d(fr, t0) + phase_inc_d(fr, t0 + 1)
           + phase_inc_d(fr, t0 + 2) + phase_inc_d(fr, t0 + 3);
#pragma unroll
  for (int off = 32; off > 0; off >>= 1) s += __shfl_xor(s, off);
  if (lane == 0) CTOT[((size_t)b * 128 + o) * 512 + ch] = s;
}

__global__ __launch_bounds__(128) void phaseB4(
    const double* __restrict__ CTOT, double* __restrict__ CBAS) {
  int o = threadIdx.x;
  int b = blockIdx.x;
  const double* ct = CTOT + ((size_t)b * 128 + o) * 512;
  double* cb = CBAS + ((size_t)b * 128 + o) * 512;
  double base = 0.0;
  for (int c = 0; c < 512; ++c) { cb[c] = base; base += ct[c]; }
}

DEVFN float sinx(double ph) {
  double k = rint(ph * 0.15915494309189535);
  float r = (float)__builtin_fma(-k, 6.283185307179586, ph);
  return sinf(r);
}

// ---------------- harm: 32 oscillators per block (4 groups), x2 unroll -----
__global__ __launch_bounds__(256) void harm3(
    const double* __restrict__ FFR, const float* __restrict__ LFR32,
    const double* __restrict__ CBAS, float* __restrict__ HACC) {
  int tid = threadIdx.x, lane = tid & 63, wid = tid >> 6;
  int b = blockIdx.y, grp = blockIdx.z;
  int ch = 16 + blockIdx.x * 4 + wid;        // chunks 16..495
  int t0 = ch * 256 + lane * 4;
  const double* ffr  = FFR   + (size_t)b * 65536;
  const float*  lfr  = LFR32 + (size_t)b * 65536;
  const double* cbas = CBAS  + (size_t)b * 65536;

  int fis[4]; float wls[4];
#pragma unroll
  for (int k = 0; k < 4; ++k) {
    double c = ((double)(t0 + k) + 0.5) * (1.0 / 256.0) - 0.5;
    double fl = floor(c);
    fis[k] = (int)fl;                        // [15,495] for t>=4096
    wls[k] = (float)(c - fl);
  }
  float acc0 = 0.f, acc1 = 0.f, acc2 = 0.f, acc3 = 0.f;

  for (int oo = 0; oo < 32; oo += 2) {
    int o0 = grp * 32 + oo;
    const double* fr0 = ffr + (size_t)o0 * 512;
    const double* fr1 = fr0 + 512;
    double a00 = phase_inc_d(fr0, t0+0), a10 = phase_inc_d(fr1, t0+0);
    double a01 = phase_inc_d(fr0, t0+1), a11 = phase_inc_d(fr1, t0+1);
    double a02 = phase_inc_d(fr0, t0+2), a12 = phase_inc_d(fr1, t0+2);
    double a03 = phase_inc_d(fr0, t0+3), a13 = phase_inc_d(fr1, t0+3);
    double l00 = a00, l01 = l00+a01, l02 = l01+a02, l03 = l02+a03;
    double l10 = a10, l11 = l10+a11, l12 = l11+a12, l13 = l12+a13;
    double v0 = l03, v1 = l13;
#pragma unroll
    for (int off = 1; off < 64; off <<= 1) {
      double n0 = __shfl_up(v0, off);
      double n1 = __shfl_up(v1, off);
      if (lane >= off) { v0 += n0; v1 += n1; }
    }
    double e0 = cbas[(size_t)o0 * 512 + ch] + (v0 - l03);
    double e1 = cbas[(size_t)(o0+1) * 512 + ch] + (v1 - l13);

    const float* lr0 = lfr + (size_t)o0 * 512;
    const float* lr1 = lr0 + 512;
    float lv00 = lr0[fis[0]]*(1.f-wls[0]) + lr0[fis[0]+1]*wls[0];
    float lv01 = lr0[fis[1]]*(1.f-wls[1]) + lr0[fis[1]+1]*wls[1];
    float lv02 = lr0[fis[2]]*(1.f-wls[2]) + lr0[fis[2]+1]*wls[2];
    float lv03 = lr0[fis[3]]*(1.f-wls[3]) + lr0[fis[3]+1]*wls[3];
    float lv10 = lr1[fis[0]]*(1.f-wls[0]) + lr1[fis[0]+1]*wls[0];
    float lv11 = lr1[fis[1]]*(1.f-wls[1]) + lr1[fis[1]+1]*wls[1];
    float lv12 = lr1[fis[2]]*(1.f-wls[2]) + lr1[fis[2]+1]*wls[2];
    float lv13 = lr1[fis[3]]*(1.f-wls[3]) + lr1[fis[3]+1]*wls[3];

    float s00 = sinx(e0 + l00), s01 = sinx(e0 + l01);
    float s02 = sinx(e0 + l02), s03 = sinx(e0 + l03);
    float s10 = sinx(e1 + l10), s11 = sinx(e1 + l11);
    float s12 = sinx(e1 + l12), s13 = sinx(e1 + l13);
    acc0 = fmaf(s00, lv00, acc0); acc0 = fmaf(s10, lv10, acc0);
    acc1 = fmaf(s01, lv01, acc1); acc1 = fmaf(s11, lv11, acc1);
    acc2 = fmaf(s02, lv02, acc2); acc2 = fmaf(s12, lv12, acc2);
    acc3 = fmaf(s03, lv03, acc3); acc3 = fmaf(s13, lv13, acc3);
  }
  float* ha = HACC + ((size_t)grp * 4 + b) * 122880 + (t0 - 4096);
  ha[0] = acc0; ha[1] = acc1; ha[2] = acc2; ha[3] = acc3;
}

// ---------------- finalize: sum 4 osc-group partials + noise OLA -----------
__global__ __launch_bounds__(256) void finz(
    const float* __restrict__ HACC, const float* __restrict__ FILT,
    float* __restrict__ out) {
  int i = blockIdx.x * 256 + threadIdx.x;      // 0..491519
  int b = i / 122880;
  int j = i - b * 122880;
  int t = j + 4096;
  float h = ((HACC[(size_t)(0*4+b)*122880 + j]
            + HACC[(size_t)(1*4+b)*122880 + j])
            + HACC[(size_t)(2*4+b)*122880 + j])
            + HACC[(size_t)(3*4+b)*122880 + j];
  int r = t >> 4, jj = t & 15;
  const float* filt = FILT + (size_t)b * 262144;
  float nz = filt[r * 32 + jj] + filt[(r - 1) * 32 + 16 + jj];
  out[i] = h + nz;
}

// ---------------------------------------------------------------------------
extern "C" void kernel_launch(void* const* d_in, const int* in_sizes, int n_in,
                              void* d_out, int out_size, void* d_ws, size_t ws_size,
                              hipStream_t stream) {
  (void)out_size; (void)ws_size;
  const float *big0 = nullptr, *big1 = nullptr;
  const float *m1w=nullptr,*m2w=nullptr,*m3w=nullptr,*m4w=nullptr,*m5w=nullptr;
  const float *tpw=nullptr,*n1w=nullptr,*n2w=nullptr,*n3w=nullptr,*n4w=nullptr;
  const float *centers=nullptr,*erbs=nullptr;
  int n55296 = 0, n128 = 0, nbig = 0;
  for (int i = 0; i < n_in; ++i) {
    const float* p = (const float*)d_in[i];
    switch (in_sizes[i]) {
      case 524288: if (nbig++ == 0) big0 = p; else big1 = p; break;
      case 864:    m1w = p; break;
      case 27648:  m2w = p; break;
      case 55296:  if (n55296++ == 0) m3w = p; else m5w = p; break;
      case 110592: m4w = p; break;
      case 576:    tpw = p; break;
      case 26112:  n1w = p; break;
      case 13056:  n2w = p; break;
      case 1536:   n3w = p; break;
      case 2448:   n4w = p; break;
      case 128:    if (n128++ == 0) centers = p; else erbs = p; break;
      default: break;
    }
  }

  char* ws = (char*)d_ws;
  float*  R1f   = (float*) (ws + 0);           // 64MB: 2 x 8,388,608 els
  float*  R2f   = (float*) (ws + 67108864);    // 32MB: 2 x 4,194,304
  float*  PREf  = (float*) (ws + 100663296);   // 16MB: 2 x 2,097,152
  float*  Pf    = (float*) (ws + 117440512);   // 1MB:  2 x 131,072
  float*  NB1   = (float*) (ws + 118489088);   // 1MB:  2 x 131,072
  float*  NB2   = (float*) (ws + 119537664);   // 2MB:  2 x 262,144
  float*  NB3   = (float*) (ws + 121634816);   // 1MB:  2 x 131,072
  float*  MAGS  = (float*) (ws + 122683392);   // 1.12MB: 2 x 139,264
  double* FFR   = (double*)(ws + 123863040);   // 2MB (x4 batches)
  float*  LFR32 = (float*) (ws + 125960192);   // 1MB (x4)
  double* CTOT  = (double*)(ws + 127008768);   // 2MB (x4)
  double* CBAS  = (double*)(ws + 129105920);   // 2MB (x4)
  float*  FILT  = (float*) (ws + 131203072);   // 4MB (x4)
  float*  HACC  = (float*) (ws + 135397376);   // 7.9MB
  float*  XBUF  = (float*) (ws + 143261696);   // 2MB
  float*  NZBUF = (float*) (ws + 145358848);   // 2MB
  int*    FLAGI = (int*)   (ws + 147456000);
  // NB1R aliased onto R1f: live range [resizefz -> convz n2] is strictly
  // after R1f's last read (m4) and before its next write (next group's m1).
  float*  NB1R  = R1f;                         // 16MB used of 64MB region

  zeroi<<<dim3(1),64,0,stream>>>(FLAGI);
  pickmax<<<dim3(256),256,0,stream>>>(big0, FLAGI);
  selcopy<<<dim3(2048),256,0,stream>>>(big0, big1, FLAGI, XBUF, NZBUF);

  const size_t S_R1 = 8388608, S_R2 = 4194304, S_PRE = 2097152;
  const size_t S_P = 131072, S_NB1 = 131072, S_NB1R = 2097152;
  const size_t S_NB2 = 262144, S_NB3 = 131072, S_MAGS = 139264;

  for (int g = 0; g < 2; ++g) {
    const float* xg = XBUF + (size_t)g * 2 * 131072;
    // trunk (f64 accumulate, f32 storage), z = 2 batches
    convz<1,32,3,9,1,1,4, 8,4,1><<<dim3(4,256,2),128,0,stream>>>(xg, m1w, R1f, 256,512,256,512, 131072, S_R1);
    convz<32,32,9,3,1,4,1, 8,4,1><<<dim3(4,256,2),128,0,stream>>>(R1f, m2w, R2f, 256,512,256,512, S_R1, S_R2);
    convz<32,64,3,9,1,1,4, 8,4,1><<<dim3(8,256,2),128,0,stream>>>(R2f, m3w, R1f, 256,512,256,512, S_R2, S_R1);
    convz<64,64,3,9,2,1,4, 8,4,1><<<dim3(8,128,2),128,0,stream>>>(R1f, m4w, R2f, 256,512,128,512, S_R1, S_R2);
    convz<64,32,3,9,1,1,4, 8,4,1><<<dim3(4,128,2),128,0,stream>>>(R2f, m5w, PREf, 128,512,128,512, S_R2, S_PRE);
    convz<32,2,3,3,1,1,1, 2,4,0><<<dim3(1,128,2),128,0,stream>>>(PREf, tpw, Pf, 128,512,128,512, S_PRE, S_P);
    tpostz<<<dim3(256,2),256,0,stream>>>(Pf, centers, erbs, LFR32, FFR, g);
    // noise branch (f32), z = 2 batches   [R1f dead from here to group end]
    convz<32,16,17,3,8,8,1, 4,1,1><<<dim3(16,16,2),128,0,stream>>>(PREf, n1w, NB1, 128,512,16,512, S_PRE, S_NB1);
    resizefz<<<dim3(8192,2),256,0,stream>>>(NB1, NB1R);
    convz<16,16,17,3,8,8,1, 4,4,1><<<dim3(64,2,2),128,0,stream>>>(NB1R, n2w, NB2, 16,8192,2,8192, S_NB1R, S_NB2);
    convz<16,16,2,3,1,0,1, 4,4,1><<<dim3(64,1,2),128,0,stream>>>(NB2, n3w, NB3, 2,8192,1,8192, S_NB2, S_NB3);
    convz<16,17,3,3,1,1,1, 1,4,2><<<dim3(272,1,2),128,0,stream>>>(NB3, n4w, MAGS, 1,8192,1,8192, S_NB3, S_MAGS);
    noisebankz<<<dim3(32,2),256,0,stream>>>(NZBUF, MAGS, FILT, g);
  }

  // phases + harmonic over all 4 batches
  phaseA256<<<dim3(128,128,4),256,0,stream>>>(FFR, CTOT);
  phaseB4<<<dim3(4),128,0,stream>>>(CTOT, CBAS);
  harm3<<<dim3(120,4,4),256,0,stream>>>(FFR, LFR32, CBAS, HACC);
  finz<<<dim3(1920),256,0,stream>>>(HACC, FILT, (float*)d_out);
}